// Round 4
// baseline (283.095 us; speedup 1.0000x reference)
//
#include <hip/hip_runtime.h>

// Problem constants: B=2048, V=256, T=11, K=8, N=8, H=255
constexpr int B_ = 2048;
constexpr int V_ = 256;
constexpr int T_ = 11;
constexpr int K_ = 8;
constexpr int N_ = 8;
constexpr int H_ = 255;
constexpr int TK = T_ * K_;          // 88 (t*8+k flat index within a b)
constexpr int XB = V_ * TK;          // 22528 floats per batch element
constexpr int SLAB = 92;             // hsh per-k stride: 28k%32 distinct -> b128 reads conflict-free

// ---------------- fused kernel: scan -> gather -> MLP ----------------
// One block per b; grid 2048 at 4 blocks/CU = exactly 2.0 resident block-waves.
// Phase A: scan the 88 KB one-hot slab (coalesced float4) -> LDS ids
//          (no atomics: exactly one nonzero per (t,k)).
// Phase B: gather scanner_w directly (64 KB table, L2-resident) with inline ReLU.
//          Valid because one-hot coefficient is exactly 1.0: h = relu(sw[n,id,k]).
// Phase C: hidden+output MLP; hreg register cache split into two t-halves to
//          stay under 128 VGPRs (4 blocks/CU). Butterfly reduce, 22 outputs.
__global__ __launch_bounds__(256, 4)
void scanner_fused(const float* __restrict__ x,    // (B,V,T,K)
                   const float* __restrict__ sw,   // (N,V,K)
                   const float* __restrict__ hw,   // (K*H, N)
                   const float* __restrict__ ow,   // (2, K*H)
                   const float* __restrict__ ob,   // (2,)
                   float* __restrict__ out)        // (B,2,T)
{
    __shared__ int   ids_sh[TK];       // 88
    __shared__ float hsh[K_ * SLAB];   // 736 floats: [k][t*8+n], ReLU'd
    __shared__ float wred[4][22];

    const int tid = threadIdx.x;
    const int b   = blockIdx.x;

    // ---- phase A: scan slab for one-hot indices ----
    const float4* xb = (const float4*)(x + (size_t)b * XB);
    #pragma unroll
    for (int c = 0; c < 3; ++c) {
        const int nload = (c < 2) ? 8 : 6;   // 22 float4/thread total
        float4 vbuf[8];
        #pragma unroll
        for (int i = 0; i < 8; ++i)
            if (i < nload) vbuf[i] = xb[(c * 8 + i) * 256 + tid];
        #pragma unroll
        for (int i = 0; i < 8; ++i) {
            if (i < nload) {
                const float4 q = vbuf[i];
                if ((q.x + q.y) + (q.z + q.w) != 0.0f) {   // values exactly 0.0/1.0
                    const int F = ((c * 8 + i) * 256 + tid) * 4;
                    if (q.x != 0.0f) { const int f = F;     const int v = f / TK; ids_sh[f - v * TK] = v; }
                    if (q.y != 0.0f) { const int f = F + 1; const int v = f / TK; ids_sh[f - v * TK] = v; }
                    if (q.z != 0.0f) { const int f = F + 2; const int v = f / TK; ids_sh[f - v * TK] = v; }
                    if (q.w != 0.0f) { const int f = F + 3; const int v = f / TK; ids_sh[f - v * TK] = v; }
                }
            }
        }
    }
    __syncthreads();

    // ---- phase B: gather sw rows (L2-resident 64 KB) into hsh, inline ReLU ----
    if (tid < TK) {
        const int v = ids_sh[tid];
        const int t = tid >> 3;
        const int k = tid & 7;
        float* d = hsh + k * SLAB + t * 8;
        #pragma unroll
        for (int n = 0; n < N_; ++n)
            d[n] = fmaxf(sw[(n * V_ + v) * K_ + k], 0.0f);
    }
    __syncthreads();

    // ---- phase C: hidden layer + output accumulation (t split in halves) ----
    const int k2 = tid >> 5;   // slot 0..7
    const int hb = tid & 31;

    float acc0[T_], acc1[T_];
    #pragma unroll
    for (int t = 0; t < T_; ++t) { acc0[t] = 0.0f; acc1[t] = 0.0f; }

    #pragma unroll
    for (int half = 0; half < 2; ++half) {
        const int t0 = (half == 0) ? 0 : 6;
        const int t1 = (half == 0) ? 6 : T_;

        float hreg[6][N_];     // broadcast b128 LDS reads (same addr per k2 group)
        for (int t = t0; t < t1; ++t) {
            const float4* p = (const float4*)(hsh + k2 * SLAB + t * 8);
            const float4 a0 = p[0];
            const float4 a1 = p[1];
            float* hr = hreg[t - t0];
            hr[0] = a0.x; hr[1] = a0.y; hr[2] = a0.z; hr[3] = a0.w;
            hr[4] = a1.x; hr[5] = a1.y; hr[6] = a1.z; hr[7] = a1.w;
        }

        #pragma unroll
        for (int i = 0; i < 8; ++i) {
            const int hh = hb + 32 * i;          // 0..255, skip 255
            if (hh < H_) {
                const int row = k2 * H_ + hh;    // coalesced across hb; L1-hot 2nd half
                const float4* hwp = (const float4*)(hw + row * 8);
                const float4 w0 = hwp[0];
                const float4 w1 = hwp[1];
                const float o0 = ow[row];
                const float o1 = ow[K_ * H_ + row];
                for (int t = t0; t < t1; ++t) {
                    const float* hr = hreg[t - t0];
                    float pre = w0.x * hr[0];
                    pre = fmaf(w0.y, hr[1], pre);
                    pre = fmaf(w0.z, hr[2], pre);
                    pre = fmaf(w0.w, hr[3], pre);
                    pre = fmaf(w1.x, hr[4], pre);
                    pre = fmaf(w1.y, hr[5], pre);
                    pre = fmaf(w1.z, hr[6], pre);
                    pre = fmaf(w1.w, hr[7], pre);
                    const float h2 = fmaxf(pre, 0.0f);
                    acc0[t] = fmaf(h2, o0, acc0[t]);
                    acc1[t] = fmaf(h2, o1, acc1[t]);
                }
            }
        }
    }

    // ---- reduce: 64-lane butterfly, then cross-wave ----
    #pragma unroll
    for (int t = 0; t < T_; ++t) {
        #pragma unroll
        for (int off = 32; off >= 1; off >>= 1) {
            acc0[t] += __shfl_xor(acc0[t], off, 64);
            acc1[t] += __shfl_xor(acc1[t], off, 64);
        }
    }
    const int wave = tid >> 6;
    const int lane = tid & 63;
    if (lane == 0) {
        #pragma unroll
        for (int t = 0; t < T_; ++t) {
            wred[wave][t]      = acc0[t];
            wred[wave][11 + t] = acc1[t];
        }
    }
    __syncthreads();

    if (tid < 22) {
        const float s = wred[0][tid] + wred[1][tid] + wred[2][tid] + wred[3][tid];
        out[(size_t)b * 22 + tid] = s + ob[tid / 11];
    }
}

extern "C" void kernel_launch(void* const* d_in, const int* in_sizes, int n_in,
                              void* d_out, int out_size, void* d_ws, size_t ws_size,
                              hipStream_t stream) {
    const float* x  = (const float*)d_in[0];  // (B,V,T,K)
    const float* sw = (const float*)d_in[1];  // (N,V,K)
    const float* hw = (const float*)d_in[2];  // (K*H,N)
    const float* ow = (const float*)d_in[3];  // (2,K*H)
    const float* ob = (const float*)d_in[4];  // (2,)
    float* out = (float*)d_out;               // (B,2,T)

    scanner_fused<<<B_, 256, 0, stream>>>(x, sw, hw, ow, ob, out);
}

// Round 5
// 271.744 us; speedup vs baseline: 1.0418x; 1.0418x over previous
//
#include <hip/hip_runtime.h>

// Problem constants: B=2048, V=256, T=11, K=8, N=8, H=255
constexpr int B_ = 2048;
constexpr int V_ = 256;
constexpr int T_ = 11;
constexpr int K_ = 8;
constexpr int N_ = 8;
constexpr int H_ = 255;
constexpr int TK = T_ * K_;          // 88 (t*8+k flat index within a b)
constexpr int XB = V_ * TK;          // 22528 floats per batch element
constexpr int SLAB = 92;             // hsh per-k stride: 28k%32 distinct -> b128 reads conflict-free

// ---------------- fused kernel: scan -> gather -> MLP ----------------
// One block per b, 3 blocks/CU (R3's known-good phase-C register shape; the
// R4 t-half split caused scratch demotion via variable-index hreg/acc).
// Phase A: scan the 88 KB one-hot slab (coalesced float4) -> LDS ids
//          (no atomics: exactly one nonzero per (t,k)).
// Phase B: gather scanner_w directly with inline ReLU — 704 scalar loads
//          spread across all 256 threads (64 KB table, L1/L2-resident).
//          Valid because one-hot coefficient is exactly 1.0: h = relu(sw[n,id,k]).
// Phase C: hidden+output MLP, fully unrolled hreg[11][8] cache; butterfly reduce.
__global__ __launch_bounds__(256, 3)
void scanner_fused(const float* __restrict__ x,    // (B,V,T,K)
                   const float* __restrict__ sw,   // (N,V,K)
                   const float* __restrict__ hw,   // (K*H, N)
                   const float* __restrict__ ow,   // (2, K*H)
                   const float* __restrict__ ob,   // (2,)
                   float* __restrict__ out)        // (B,2,T)
{
    __shared__ int   ids_sh[TK];       // 88
    __shared__ float hsh[K_ * SLAB];   // 736 floats: [k][t*8+n], ReLU'd
    __shared__ float wred[4][22];

    const int tid = threadIdx.x;
    const int b   = blockIdx.x;

    // ---- phase A: scan slab for one-hot indices ----
    const float4* xb = (const float4*)(x + (size_t)b * XB);
    #pragma unroll
    for (int c = 0; c < 3; ++c) {
        const int nload = (c < 2) ? 8 : 6;   // 22 float4/thread total
        float4 vbuf[8];
        #pragma unroll
        for (int i = 0; i < 8; ++i)
            if (i < nload) vbuf[i] = xb[(c * 8 + i) * 256 + tid];
        #pragma unroll
        for (int i = 0; i < 8; ++i) {
            if (i < nload) {
                const float4 q = vbuf[i];
                if ((q.x + q.y) + (q.z + q.w) != 0.0f) {   // values exactly 0.0/1.0
                    const int F = ((c * 8 + i) * 256 + tid) * 4;
                    if (q.x != 0.0f) { const int f = F;     const int v = f / TK; ids_sh[f - v * TK] = v; }
                    if (q.y != 0.0f) { const int f = F + 1; const int v = f / TK; ids_sh[f - v * TK] = v; }
                    if (q.z != 0.0f) { const int f = F + 2; const int v = f / TK; ids_sh[f - v * TK] = v; }
                    if (q.w != 0.0f) { const int f = F + 3; const int v = f / TK; ids_sh[f - v * TK] = v; }
                }
            }
        }
    }
    __syncthreads();

    // ---- phase B: gather sw (L1/L2-resident 64 KB) into hsh, inline ReLU ----
    // 88 entries x 8 n = 704 scalar loads spread over 256 threads (<=3 each).
    #pragma unroll
    for (int j = 0; j < 3; ++j) {
        const int idx = j * 256 + tid;
        if (idx < TK * N_) {
            const int entry = idx >> 3;       // 0..87
            const int n     = idx & 7;
            const int t     = entry >> 3;
            const int k     = entry & 7;
            const int v     = ids_sh[entry];
            hsh[k * SLAB + t * 8 + n] = fmaxf(sw[(n * V_ + v) * K_ + k], 0.0f);
        }
    }
    __syncthreads();

    // ---- phase C: hidden layer + output accumulation (R3 shape) ----
    const int k2 = tid >> 5;   // slot 0..7
    const int hb = tid & 31;

    float hreg[T_][N_];        // broadcast b128 LDS reads (same addr per k2 group)
    #pragma unroll
    for (int t = 0; t < T_; ++t) {
        const float4* p = (const float4*)(hsh + k2 * SLAB + t * 8);
        const float4 a0 = p[0];
        const float4 a1 = p[1];
        hreg[t][0] = a0.x; hreg[t][1] = a0.y; hreg[t][2] = a0.z; hreg[t][3] = a0.w;
        hreg[t][4] = a1.x; hreg[t][5] = a1.y; hreg[t][6] = a1.z; hreg[t][7] = a1.w;
    }

    float acc0[T_], acc1[T_];
    #pragma unroll
    for (int t = 0; t < T_; ++t) { acc0[t] = 0.0f; acc1[t] = 0.0f; }

    #pragma unroll
    for (int i = 0; i < 8; ++i) {
        const int hh = hb + 32 * i;          // 0..255, skip 255
        if (hh < H_) {
            const int row = k2 * H_ + hh;    // coalesced across hb
            const float4* hwp = (const float4*)(hw + row * 8);
            const float4 w0 = hwp[0];
            const float4 w1 = hwp[1];
            const float o0 = ow[row];
            const float o1 = ow[K_ * H_ + row];
            #pragma unroll
            for (int t = 0; t < T_; ++t) {
                float pre = w0.x * hreg[t][0];
                pre = fmaf(w0.y, hreg[t][1], pre);
                pre = fmaf(w0.z, hreg[t][2], pre);
                pre = fmaf(w0.w, hreg[t][3], pre);
                pre = fmaf(w1.x, hreg[t][4], pre);
                pre = fmaf(w1.y, hreg[t][5], pre);
                pre = fmaf(w1.z, hreg[t][6], pre);
                pre = fmaf(w1.w, hreg[t][7], pre);
                const float h2 = fmaxf(pre, 0.0f);
                acc0[t] = fmaf(h2, o0, acc0[t]);
                acc1[t] = fmaf(h2, o1, acc1[t]);
            }
        }
    }

    // ---- reduce: 64-lane butterfly, then cross-wave ----
    #pragma unroll
    for (int t = 0; t < T_; ++t) {
        #pragma unroll
        for (int off = 32; off >= 1; off >>= 1) {
            acc0[t] += __shfl_xor(acc0[t], off, 64);
            acc1[t] += __shfl_xor(acc1[t], off, 64);
        }
    }
    const int wave = tid >> 6;
    const int lane = tid & 63;
    if (lane == 0) {
        #pragma unroll
        for (int t = 0; t < T_; ++t) {
            wred[wave][t]      = acc0[t];
            wred[wave][11 + t] = acc1[t];
        }
    }
    __syncthreads();

    if (tid < 22) {
        const float s = wred[0][tid] + wred[1][tid] + wred[2][tid] + wred[3][tid];
        out[(size_t)b * 22 + tid] = s + ob[tid / 11];
    }
}

extern "C" void kernel_launch(void* const* d_in, const int* in_sizes, int n_in,
                              void* d_out, int out_size, void* d_ws, size_t ws_size,
                              hipStream_t stream) {
    const float* x  = (const float*)d_in[0];  // (B,V,T,K)
    const float* sw = (const float*)d_in[1];  // (N,V,K)
    const float* hw = (const float*)d_in[2];  // (K*H,N)
    const float* ow = (const float*)d_in[3];  // (2,K*H)
    const float* ob = (const float*)d_in[4];  // (2,)
    float* out = (float*)d_out;               // (B,2,T)

    scanner_fused<<<B_, 256, 0, stream>>>(x, sw, hw, ow, ob, out);
}